// Round 1
// baseline (49.302 us; speedup 1.0000x reference)
//
#include <hip/hip_runtime.h>

#define NUM_EMBEDDINGS 50000
#define EMBEDDING_DIM  1024
#define N_CENTROIDS    256
#define BLOCK_SIZE_PQ  8
#define N_BLOCKS       128   // EMBEDDING_DIM / BLOCK_SIZE_PQ
#define BATCH          8
#define SEQ            2048
#define N_TOKENS       (BATCH * SEQ)   // 16384

// One 256-thread block per token. Each thread writes one float4 of the
// token's 1024-float embedding row (256 float4s, fully coalesced).
//   d = tid*4 .. tid*4+3  where d = blk*8 + half*4 + (0..3)
//   blk = tid>>1, half = tid&1
//   code = assignments[blk*NUM_EMBEDDINGS + id]
//   value = centroids[code][half*4 .. half*4+3]  (= float4 #(code*2+half))
__global__ __launch_bounds__(256) void pq_embed_kernel(
    const float* __restrict__ centroids,     // [256, 8]
    const int*   __restrict__ assignments,   // [128 * 50000]
    const int*   __restrict__ input_ids,     // [16384]
    float*       __restrict__ out)           // [16384, 1024]
{
    const int token = blockIdx.x;
    const int tid   = threadIdx.x;

    // Broadcast token id (scalar load — same address for all lanes).
    const int id = input_ids[token];

    const int blk  = tid >> 1;
    const int half = tid & 1;

    const int code = assignments[blk * NUM_EMBEDDINGS + id];

    const float4* __restrict__ c4 = reinterpret_cast<const float4*>(centroids);
    float4 v = c4[(code << 1) + half];

    float4* __restrict__ o4 = reinterpret_cast<float4*>(out);
    o4[token * (EMBEDDING_DIM / 4) + tid] = v;
}

extern "C" void kernel_launch(void* const* d_in, const int* in_sizes, int n_in,
                              void* d_out, int out_size, void* d_ws, size_t ws_size,
                              hipStream_t stream) {
    const float* centroids   = (const float*)d_in[0];
    const int*   assignments = (const int*)d_in[1];
    const int*   input_ids   = (const int*)d_in[2];
    float*       out         = (float*)d_out;

    dim3 grid(N_TOKENS);
    dim3 block(256);
    pq_embed_kernel<<<grid, block, 0, stream>>>(centroids, assignments, input_ids, out);
}

// Round 2
// 27.087 us; speedup vs baseline: 1.8202x; 1.8202x over previous
//
#include <hip/hip_runtime.h>

#define NUM_EMBEDDINGS 50000
#define EMBEDDING_DIM  1024
#define N_CENTROIDS    256
#define N_BLOCKS       128   // EMBEDDING_DIM / 8
#define N_TOKENS       16384 // BATCH * SEQ

// ---------------- Kernel 1: transpose + narrow the code table ----------------
// in : assign [N_BLOCKS][NUM_EMBEDDINGS] int32 (values 0..255)
// out: codes8 [NUM_EMBEDDINGS][N_BLOCKS] uint8  (one 128 B line per embedding id)
//
// Tile: 128 blks x 64 ids staged in LDS (int, rows padded to 65 -> read-phase
// writes are 2-way (free), write-phase reads ~4-way (1.58x, negligible here)).
__global__ __launch_bounds__(256) void transpose_codes_kernel(
    const int* __restrict__ assign,
    unsigned char* __restrict__ codes8)
{
    __shared__ int tile[N_BLOCKS][65];   // [blk][id_local]

    const int t = threadIdx.x;
    const int id_base = blockIdx.x * 64;

    // Read phase: 8 iters x (16 blks x 16 int4) = 128 blks x 64 ids.
    // Coalesced: each 16-thread group reads 256 B contiguous of one blk row.
    const int blk_r = t >> 4;   // 0..15
    const int idq   = t & 15;   // int4 column 0..15
    #pragma unroll
    for (int it = 0; it < 8; ++it) {
        const int blk = it * 16 + blk_r;
        const int id  = id_base + idq * 4;
        if (id + 3 < NUM_EMBEDDINGS) {   // NUM_EMBEDDINGS % 4 == 0 -> all-or-nothing
            const int4 v = *reinterpret_cast<const int4*>(&assign[blk * NUM_EMBEDDINGS + id]);
            tile[blk][idq * 4 + 0] = v.x;
            tile[blk][idq * 4 + 1] = v.y;
            tile[blk][idq * 4 + 2] = v.z;
            tile[blk][idq * 4 + 3] = v.w;
        }
    }
    __syncthreads();

    // Write phase: 8 iters x (8 ids x 32 uchar4) = 64 ids x 128 blks.
    // Each half-wave writes one id's 128 B row contiguously (coalesced).
    const int c4      = t & 31;  // uchar4 column: blks c4*4 .. c4*4+3
    const int id_part = t >> 5;  // 0..7
    #pragma unroll
    for (int it = 0; it < 8; ++it) {
        const int id_l = it * 8 + id_part;
        const int id_g = id_base + id_l;
        if (id_g < NUM_EMBEDDINGS) {
            const unsigned int b0 = (unsigned int)tile[c4 * 4 + 0][id_l] & 0xFFu;
            const unsigned int b1 = (unsigned int)tile[c4 * 4 + 1][id_l] & 0xFFu;
            const unsigned int b2 = (unsigned int)tile[c4 * 4 + 2][id_l] & 0xFFu;
            const unsigned int b3 = (unsigned int)tile[c4 * 4 + 3][id_l] & 0xFFu;
            reinterpret_cast<unsigned int*>(codes8)[id_g * (N_BLOCKS / 4) + c4] =
                b0 | (b1 << 8) | (b2 << 16) | (b3 << 24);
        }
    }
}

// ---------------- Kernel 2: embedding gather ----------------
// One 256-thread block per token; thread t writes output float4 #t.
// All 128 codes for a token live in one 128 B line of codes8.
__global__ __launch_bounds__(256) void pq_gather_kernel(
    const float* __restrict__ centroids,          // [256][8]
    const unsigned char* __restrict__ codes8,     // [50000][128]
    const int* __restrict__ input_ids,            // [16384]
    float* __restrict__ out)                      // [16384][1024]
{
    const int token = blockIdx.x;
    const int tid   = threadIdx.x;

    const int id   = input_ids[token];
    const int code = codes8[id * N_BLOCKS + (tid >> 1)];

    const float4 v = reinterpret_cast<const float4*>(centroids)[(code << 1) + (tid & 1)];
    reinterpret_cast<float4*>(out)[token * (EMBEDDING_DIM / 4) + tid] = v;
}

// ---------------- Fallback (R1 kernel) if ws is too small ----------------
__global__ __launch_bounds__(256) void pq_embed_fallback(
    const float* __restrict__ centroids,
    const int*   __restrict__ assignments,
    const int*   __restrict__ input_ids,
    float*       __restrict__ out)
{
    const int token = blockIdx.x;
    const int tid   = threadIdx.x;
    const int id    = input_ids[token];
    const int code  = assignments[(tid >> 1) * NUM_EMBEDDINGS + id];
    const float4 v  = reinterpret_cast<const float4*>(centroids)[(code << 1) + (tid & 1)];
    reinterpret_cast<float4*>(out)[token * (EMBEDDING_DIM / 4) + tid] = v;
}

extern "C" void kernel_launch(void* const* d_in, const int* in_sizes, int n_in,
                              void* d_out, int out_size, void* d_ws, size_t ws_size,
                              hipStream_t stream) {
    const float* centroids   = (const float*)d_in[0];
    const int*   assignments = (const int*)d_in[1];
    const int*   input_ids   = (const int*)d_in[2];
    float*       out         = (float*)d_out;

    const size_t ws_needed = (size_t)NUM_EMBEDDINGS * N_BLOCKS;  // 6.4 MB of uint8
    if (ws_size >= ws_needed) {
        unsigned char* codes8 = (unsigned char*)d_ws;
        const int n_tiles = (NUM_EMBEDDINGS + 63) / 64;  // 782
        transpose_codes_kernel<<<n_tiles, 256, 0, stream>>>(assignments, codes8);
        pq_gather_kernel<<<N_TOKENS, 256, 0, stream>>>(centroids, codes8, input_ids, out);
    } else {
        pq_embed_fallback<<<N_TOKENS, 256, 0, stream>>>(centroids, assignments, input_ids, out);
    }
}

// Round 3
// 25.753 us; speedup vs baseline: 1.9144x; 1.0518x over previous
//
#include <hip/hip_runtime.h>

#define NUM_EMBEDDINGS 50000
#define EMBEDDING_DIM  1024
#define N_CENTROIDS    256
#define N_BLOCKS       128    // EMBEDDING_DIM / 8
#define N_TOKENS       16384  // BATCH * SEQ
#define N_PARTS        8      // one per XCD
#define BLKS_PER_PART  (N_BLOCKS / N_PARTS)        // 16
#define TOKENS_PER_WG  8      // 256 threads = 8 groups of 32 lanes

// Single-kernel gather with XCD-sliced reads of `assignments`.
//
// Grid: (N_TOKENS / TOKENS_PER_WG) * N_PARTS blocks of 256 threads.
//   part  = blockIdx.x & 7   -> lands on a fixed XCD (round-robin dispatch),
//                               so each XCD's L2 only caches blks [16p,16p+16)
//                               of assignments: 16 * 50000 * 4 B = 3.2 MB < 4 MB L2.
//   group = blockIdx.x >> 3  -> 8 consecutive tokens.
//
// Thread (tgrp = tid>>5, lane = tid&31):
//   token = group*8 + tgrp
//   writes out float4 #(token*256 + part*32 + lane)
//     -> d = part*128 + lane*4 + j ; blk = 16*part + (lane>>1) ; half = lane&1
//   code  = assignments[blk*NUM_EMBEDDINGS + id]   (4 B scattered, XCD-local L2)
//   value = centroids float4 #(code*2 + half)      (8 KB table, L1-resident)
__global__ __launch_bounds__(256) void pq_embed_xcd_kernel(
    const float* __restrict__ centroids,     // [256][8]
    const int*   __restrict__ assignments,   // [128][50000]
    const int*   __restrict__ input_ids,     // [16384]
    float*       __restrict__ out)           // [16384][1024]
{
    const int part  = blockIdx.x & (N_PARTS - 1);
    const int group = blockIdx.x >> 3;

    const int tid  = threadIdx.x;
    const int tgrp = tid >> 5;
    const int lane = tid & 31;

    const int token = group * TOKENS_PER_WG + tgrp;
    const int id    = input_ids[token];

    const int blk  = part * BLKS_PER_PART + (lane >> 1);
    const int half = lane & 1;

    const int code = assignments[blk * NUM_EMBEDDINGS + id];

    const float4 v = reinterpret_cast<const float4*>(centroids)[(code << 1) + half];

    reinterpret_cast<float4*>(out)[token * (EMBEDDING_DIM / 4) + part * 32 + lane] = v;
}

extern "C" void kernel_launch(void* const* d_in, const int* in_sizes, int n_in,
                              void* d_out, int out_size, void* d_ws, size_t ws_size,
                              hipStream_t stream) {
    const float* centroids   = (const float*)d_in[0];
    const int*   assignments = (const int*)d_in[1];
    const int*   input_ids   = (const int*)d_in[2];
    float*       out         = (float*)d_out;

    dim3 grid((N_TOKENS / TOKENS_PER_WG) * N_PARTS);  // 2048 * 8 = 16384
    dim3 block(256);
    pq_embed_xcd_kernel<<<grid, block, 0, stream>>>(centroids, assignments, input_ids, out);
}

// Round 5
// 19.771 us; speedup vs baseline: 2.4937x; 1.3026x over previous
//
#include <hip/hip_runtime.h>

#define NUM_EMBEDDINGS 50000
#define EMBEDDING_DIM  1024
#define N_CENTROIDS    256
#define N_BLOCKS       128    // EMBEDDING_DIM / 8
#define N_TOKENS       16384  // BATCH * SEQ
#define N_PARTS        8      // one per XCD
#define BLKS_PER_PART  (N_BLOCKS / N_PARTS)        // 16
#define TOKENS_PER_WG  8      // 256 threads = 8 groups of 32 lanes

typedef float f32x4 __attribute__((ext_vector_type(4)));  // native vec: nt-builtin-compatible

// Single-kernel gather, XCD-sliced reads + NON-TEMPORAL output stores.
//
//   part  = blockIdx.x & 7   -> fixed XCD (round-robin dispatch): each XCD's
//                               L2 caches only blks [16p,16p+16) of
//                               assignments = 3.2 MB < 4 MB L2.
//   nt stores                -> 64 MB output stream does NOT allocate in L2,
//                               so the assignments slice stays resident
//                               (R3's shortfall was write-thrash evicting it).
//
// Thread (tgrp = tid>>5, lane = tid&31):
//   token = (blockIdx.x>>3)*8 + tgrp
//   blk   = 16*part + (lane>>1) ; half = lane&1
//   code  = assignments[blk*NUM_EMBEDDINGS + id]    (4 B, XCD-local L2)
//   out float4 #(token*256 + part*32 + lane) = centroids float4 #(code*2+half)
__global__ __launch_bounds__(256) void pq_embed_xcd_nt_kernel(
    const float* __restrict__ centroids,     // [256][8]
    const int*   __restrict__ assignments,   // [128][50000]
    const int*   __restrict__ input_ids,     // [16384]
    float*       __restrict__ out)           // [16384][1024]
{
    const int part  = blockIdx.x & (N_PARTS - 1);
    const int group = blockIdx.x >> 3;

    const int tid  = threadIdx.x;
    const int tgrp = tid >> 5;
    const int lane = tid & 31;

    const int token = group * TOKENS_PER_WG + tgrp;
    const int id    = input_ids[token];

    const int blk  = part * BLKS_PER_PART + (lane >> 1);
    const int half = lane & 1;

    const int code = assignments[blk * NUM_EMBEDDINGS + id];

    const f32x4 v = reinterpret_cast<const f32x4*>(centroids)[(code << 1) + half];

    f32x4* dst = reinterpret_cast<f32x4*>(out) +
                 (size_t)token * (EMBEDDING_DIM / 4) + part * 32 + lane;
    __builtin_nontemporal_store(v, dst);
}

extern "C" void kernel_launch(void* const* d_in, const int* in_sizes, int n_in,
                              void* d_out, int out_size, void* d_ws, size_t ws_size,
                              hipStream_t stream) {
    const float* centroids   = (const float*)d_in[0];
    const int*   assignments = (const int*)d_in[1];
    const int*   input_ids   = (const int*)d_in[2];
    float*       out         = (float*)d_out;

    dim3 grid((N_TOKENS / TOKENS_PER_WG) * N_PARTS);  // 16384
    dim3 block(256);
    pq_embed_xcd_nt_kernel<<<grid, block, 0, stream>>>(centroids, assignments, input_ids, out);
}